// Round 1
// baseline (1094.866 us; speedup 1.0000x reference)
//
#include <hip/hip_runtime.h>

#define NTHREADS 256
#define GMAXN 1536          // max group size (NMAX in reference)
#define EPT 12              // max edges per thread: ceil((2*1536-1)/256)
#define ZPT 6               // max nodes per thread: 1536/256
#define TVITERS 20
#define BMAX 4096

__device__ int g_off[BMAX];
__device__ int g_maxdeg;

__device__ __forceinline__ float blockSum(float v, float* red) {
  #pragma unroll
  for (int o = 32; o > 0; o >>= 1) v += __shfl_down(v, o, 64);
  int t = threadIdx.x;
  if ((t & 63) == 0) red[t >> 6] = v;
  __syncthreads();
  float tot = (red[0] + red[1]) + (red[2] + red[3]);
  __syncthreads();
  return tot;
}

__device__ __forceinline__ float blockMax(float v, float* red) {
  #pragma unroll
  for (int o = 32; o > 0; o >>= 1) v = fmaxf(v, __shfl_down(v, o, 64));
  int t = threadIdx.x;
  if ((t & 63) == 0) red[t >> 6] = v;
  __syncthreads();
  float tot = fmaxf(fmaxf(red[0], red[1]), fmaxf(red[2], red[3]));
  __syncthreads();
  return tot;
}

// K1: exclusive scan of sizes -> g_off, zero g_maxdeg. One block.
__global__ __launch_bounds__(NTHREADS) void k_scan(const int* __restrict__ sizes, int B) {
  __shared__ int part[NTHREADS];
  int t = threadIdx.x;
  int per = (B + NTHREADS - 1) / NTHREADS;
  int base = t * per;
  int acc = 0;
  for (int k = 0; k < per; ++k) {
    int i = base + k;
    if (i < B) acc += sizes[i];
  }
  part[t] = acc;
  __syncthreads();
  if (t == 0) {
    int run = 0;
    for (int i = 0; i < NTHREADS; ++i) { int tmp = part[i]; part[i] = run; run += tmp; }
    g_maxdeg = 0;
  }
  __syncthreads();
  int run = part[t];
  for (int k = 0; k < per; ++k) {
    int i = base + k;
    if (i < B) { g_off[i] = run; run += sizes[i]; }
  }
}

// K2: per-group max degree -> global atomicMax. Chain part analytic.
__global__ __launch_bounds__(NTHREADS) void k_deg(const int* __restrict__ sizes,
                                                  const int* __restrict__ edges,
                                                  int N, int B) {
  __shared__ int cnt[GMAXN];
  __shared__ int wred[4];
  int g = blockIdx.x;
  int t = threadIdx.x;
  int s = sizes[g];
  int off = g_off[g];
  for (int i = t; i < s; i += NTHREADS)
    cnt[i] = 2 - (i == 0 ? 1 : 0) - (i == s - 1 ? 1 : 0);
  __syncthreads();
  const int* re = edges + 2 * ((N - B) + off);  // this group's random edges
  for (int e = t; e < s; e += NTHREADS) {
    atomicAdd(&cnt[re[2 * e] - off], 1);
    atomicAdd(&cnt[re[2 * e + 1] - off], 1);
  }
  __syncthreads();
  int m = 0;
  for (int i = t; i < s; i += NTHREADS) m = max(m, cnt[i]);
  #pragma unroll
  for (int o = 32; o > 0; o >>= 1) m = max(m, __shfl_down(m, o, 64));
  if ((t & 63) == 0) wred[t >> 6] = m;
  __syncthreads();
  if (t == 0) {
    m = max(max(wred[0], wred[1]), max(wred[2], wred[3]));
    atomicMax(&g_maxdeg, m);
  }
}

// K3: fused 20-iter TV prox (y in LDS, u + edges in registers) + sparsemax.
__global__ __launch_bounds__(NTHREADS) void k_main(const float* __restrict__ x,
                                                   const int* __restrict__ sizes,
                                                   const int* __restrict__ edges,
                                                   float* __restrict__ out,
                                                   int N, int B) {
  __shared__ float yL[GMAXN];
  __shared__ float red[4];
  int g = blockIdx.x;
  int t = threadIdx.x;
  int s = sizes[g];
  int off = g_off[g];
  int Eloc = 2 * s - 1;
  int nchain = s - 1;
  const int* re = edges + 2 * ((N - B) + off);
  float step = 1.0f / (2.0f * (float)g_maxdeg);

  // Own edges: endpoints packed (a | b<<16), u in registers. Unroll-12 with
  // guards so both arrays stay in VGPRs (no runtime indexing).
  uint ab[EPT];
  float uu[EPT];
  #pragma unroll
  for (int k = 0; k < EPT; ++k) {
    int e = t + k * NTHREADS;
    uu[k] = 0.0f;
    uint pk = 0;
    if (e < Eloc) {
      int a, b;
      if (e < nchain) { a = e; b = e + 1; }          // chain edge, analytic
      else { int r = e - nchain; a = re[2 * r] - off; b = re[2 * r + 1] - off; }
      pk = (uint)a | ((uint)b << 16);
    }
    ab[k] = pk;
  }

  const float* xg = x + off;
  // y1 = x (u0 = 0, so the first dT scatter is skippable)
  for (int i = t; i < s; i += NTHREADS) yL[i] = xg[i];
  __syncthreads();

  for (int it = 0; it < TVITERS; ++it) {
    // u <- clip(u + step*(y[a]-y[b]), -1, 1)
    #pragma unroll
    for (int k = 0; k < EPT; ++k) {
      int e = t + k * NTHREADS;
      if (e < Eloc) {
        int a = (int)(ab[k] & 0xFFFFu);
        int b = (int)(ab[k] >> 16);
        float nu = uu[k] + step * (yL[a] - yL[b]);
        uu[k] = fminf(1.0f, fmaxf(-1.0f, nu));
      }
    }
    __syncthreads();
    // y <- x
    for (int i = t; i < s; i += NTHREADS) yL[i] = xg[i];
    __syncthreads();
    // y <- x - dT(u): y[a] -= u, y[b] += u (LDS float atomics)
    #pragma unroll
    for (int k = 0; k < EPT; ++k) {
      int e = t + k * NTHREADS;
      if (e < Eloc) {
        int a = (int)(ab[k] & 0xFFFFu);
        int b = (int)(ab[k] >> 16);
        atomicAdd(&yL[a], -uu[k]);
        atomicAdd(&yL[b], uu[k]);
      }
    }
    __syncthreads();
  }

  // Sparsemax on z = y (GAMMA = 1). z into registers.
  float zr[ZPT];
  #pragma unroll
  for (int k = 0; k < ZPT; ++k) {
    int i = t + k * NTHREADS;
    zr[k] = (i < s) ? yL[i] : -1e30f;
  }
  float m = -1e30f;
  #pragma unroll
  for (int k = 0; k < ZPT; ++k) m = fmaxf(m, zr[k]);
  m = blockMax(m, red);

  // tau* in [zmax-1, zmax): bisect f(tau) = sum(max(z-tau,0)) vs 1
  float lo = m - 1.0f, hi = m;
  for (int r = 0; r < 30; ++r) {
    float mid = 0.5f * (lo + hi);
    float f = 0.0f;
    #pragma unroll
    for (int k = 0; k < ZPT; ++k) f += fmaxf(zr[k] - mid, 0.0f);
    f = blockSum(f, red);
    if (f >= 1.0f) lo = mid; else hi = mid;
  }
  // exact refinement on the identified support: tau = (sum_支持 z - 1)/k
  float cntf = 0.0f, S = 0.0f;
  #pragma unroll
  for (int k = 0; k < ZPT; ++k) {
    if (zr[k] > lo) { cntf += 1.0f; S += zr[k]; }
  }
  cntf = blockSum(cntf, red);
  S = blockSum(S, red);
  float tau = (S - 1.0f) / cntf;

  float sf = (float)s;
  float* og = out + off;
  #pragma unroll
  for (int k = 0; k < ZPT; ++k) {
    int i = t + k * NTHREADS;
    if (i < s) og[i] = fmaxf(zr[k] - tau, 0.0f) * sf;
  }
}

extern "C" void kernel_launch(void* const* d_in, const int* in_sizes, int n_in,
                              void* d_out, int out_size, void* d_ws, size_t ws_size,
                              hipStream_t stream) {
  const float* x = (const float*)d_in[0];
  const int* sizes = (const int*)d_in[1];
  const int* edges = (const int*)d_in[2];
  float* out = (float*)d_out;
  int N = in_sizes[0];
  int B = in_sizes[1];
  (void)d_ws; (void)ws_size; (void)n_in; (void)out_size;

  k_scan<<<1, NTHREADS, 0, stream>>>(sizes, B);
  k_deg<<<B, NTHREADS, 0, stream>>>(sizes, edges, N, B);
  k_main<<<B, NTHREADS, 0, stream>>>(x, sizes, edges, out, N, B);
}